// Round 19
// baseline (99.950 us; speedup 1.0000x reference)
//
#include <hip/hip_runtime.h>

#define HID 896
#define NQ 896
#define NKV 128
#define NQKV 1152
#define NH 14
#define NKVH 2
#define GQ 7
#define DH 64
#define SEQ 2048
#define BATCH 2
#define TOK (BATCH*SEQ)

typedef __attribute__((ext_vector_type(8))) short short8;    // 8 bf16 (4 VGPRs)
typedef __attribute__((ext_vector_type(4))) float f32x4;
typedef __attribute__((ext_vector_type(4))) unsigned short us4;

__device__ __forceinline__ unsigned short f2bf(float x) {
  unsigned int u = __builtin_bit_cast(unsigned int, x);
  u = (u + 0x7fffu + ((u >> 16) & 1u)) >> 16;
  return (unsigned short)u;
}
__device__ __forceinline__ float bf2f(unsigned short b) {
  return __builtin_bit_cast(float, (unsigned int)b << 16);
}
__device__ __forceinline__ f32x4 fzero4() {
  f32x4 z; z[0]=0.f; z[1]=0.f; z[2]=0.f; z[3]=0.f; return z;
}
__device__ __forceinline__ unsigned int cvt_pk_bf16(float lo, float hi) {
  unsigned int r;
  asm("v_cvt_pk_bf16_f32 %0, %1, %2" : "=v"(r) : "v"(lo), "v"(hi));
  return r;
}
__device__ __forceinline__ void gload_lds16(const unsigned short* g, unsigned short* l) {
  __builtin_amdgcn_global_load_lds(
      (const __attribute__((address_space(1))) void*)(const void*)g,
      (__attribute__((address_space(3))) void*)(void*)l, 16, 0, 0);
}

// ---------------- fused prep: cvt + 4 weight transposes + bias + rope tables ----------------
#define CVT_BLKS 3584   // TOK*HID/4/256
#define TRN_BLKS 448    // 196 (wq) + 28 (wk) + 28 (wv) + 196 (wo)
#define BIAS_BLKS 5
#define TAB_BLKS 256    // SEQ*32/256
#define PREP_BLKS (CVT_BLKS + TRN_BLKS + BIAS_BLKS + TAB_BLKS)

__global__ void k_prep(const float* __restrict__ hs,
                       const float* __restrict__ wq, const float* __restrict__ bq,
                       const float* __restrict__ wk, const float* __restrict__ bk,
                       const float* __restrict__ wv, const float* __restrict__ bv,
                       const float* __restrict__ wo,
                       unsigned short* __restrict__ hb,
                       unsigned short* __restrict__ wqkvt,
                       unsigned short* __restrict__ wot,
                       float* __restrict__ bqkv,
                       float2* __restrict__ cs) {
  __shared__ unsigned short Ls[64*65];
  int blk = blockIdx.x, tid = threadIdx.x;
  if (blk < CVT_BLKS) {  // hidden fp32 -> bf16
    int i = blk*256 + tid;
    float4 v = ((const float4*)hs)[i];
    us4 o; o[0]=f2bf(v.x); o[1]=f2bf(v.y); o[2]=f2bf(v.z); o[3]=f2bf(v.w);
    ((us4*)hb)[i] = o;
    return;
  }
  blk -= CVT_BLKS;
  if (blk < TRN_BLKS) {  // W [K][N] fp32 -> out [N][K] bf16, 64x64 tile
    const float* W; unsigned short* out; int K, N, n0, k0;
    if (blk < 196)      { W=wq; out=wqkvt;                        K=HID; N=NQ;  int t=blk;     n0=(t%14)*64; k0=(t/14)*64; }
    else if (blk < 224) { W=wk; out=wqkvt + (size_t)NQ*HID;       K=HID; N=NKV; int t=blk-196; n0=(t%2)*64;  k0=(t/2)*64; }
    else if (blk < 252) { W=wv; out=wqkvt + (size_t)(NQ+NKV)*HID; K=HID; N=NKV; int t=blk-224; n0=(t%2)*64;  k0=(t/2)*64; }
    else                { W=wo; out=wot;                          K=NQ;  N=HID; int t=blk-252; n0=(t%14)*64; k0=(t/14)*64; }
    #pragma unroll
    for (int i = 0; i < 16; ++i) {
      int idx = i*256 + tid;
      int r = idx >> 6, c = idx & 63;
      Ls[c*65 + r] = f2bf(W[(size_t)(k0 + r)*N + n0 + c]);
    }
    __syncthreads();
    #pragma unroll
    for (int i = 0; i < 16; ++i) {
      int idx = i*256 + tid;
      int r2 = idx >> 6, c2 = idx & 63;
      out[(size_t)(n0 + r2)*K + k0 + c2] = Ls[r2*65 + c2];
    }
    return;
  }
  blk -= TRN_BLKS;
  if (blk < BIAS_BLKS) {
    int i = blk*256 + tid;
    if (i < NQKV) {
      if (i < NQ) bqkv[i] = bq[i];
      else if (i < NQ + NKV) bqkv[i] = bk[i - NQ];
      else bqkv[i] = bv[i - NQ - NKV];
    }
    return;
  }
  blk -= BIAS_BLKS;
  {  // rope tables (paired cos/sin), SEQ*32 entries
    int i = blk*256 + tid;
    int s = i >> 5, dp = i & 31;
    float inv = __expf(-(float)(2*dp) * (13.815510557964274f / 64.0f));
    float f = (float)s * inv;
    cs[i] = make_float2(cosf(f), sinf(f));
  }
}

// ---------------- GEMM: C[M][N] = A[M][K] @ Bt[N][K]^T, BM=64 BN=128 BK=64 ----------------
// 2-phase prefetch double-buffer: stage(next) || compute(cur), ONE barrier per K-step.
// OUTMODE 0: fused bias + RoPE + layout-split epilogue -> Qr/Kr/Vt (bf16).
// OUTMODE 1: plain fp32 C
template<int OUTMODE>
__global__ __launch_bounds__(256, 3) void k_gemm_bt(
    const unsigned short* __restrict__ A,
    const unsigned short* __restrict__ Bt,
    const float* __restrict__ bias,
    const float2* __restrict__ cs,
    void* __restrict__ Cout,
    unsigned short* __restrict__ Qr,
    unsigned short* __restrict__ Kr,
    unsigned short* __restrict__ Vt,
    int M, int N, int K) {
  __shared__ unsigned short As[2][64*64];    // 16 KB
  __shared__ unsigned short Bs[2][128*64];   // 32 KB
  int tid = threadIdx.x;
  int lane = tid & 63, w = tid >> 6;
  int wr = w >> 1, wc = w & 1;
  int l15 = lane & 15, l4 = lane >> 4;
  int m0 = blockIdx.y * 64, n0 = blockIdx.x * 128;

  f32x4 acc[2][4];
  #pragma unroll
  for (int i = 0; i < 2; ++i)
    #pragma unroll
    for (int j = 0; j < 4; ++j) acc[i][j] = fzero4();

  auto stage = [&](int kt, int bsel) {
    int k0 = kt << 6;
    #pragma unroll
    for (int t = 0; t < 2; ++t) {
      int chunk = t*256 + w*64 + lane;
      int row = chunk >> 3, sp = chunk & 7;
      int sl = sp ^ (row & 7);
      gload_lds16(A + (size_t)(m0+row)*K + k0 + sl*8, &As[bsel][(t*256 + w*64)*8]);
    }
    #pragma unroll
    for (int t = 0; t < 4; ++t) {
      int chunk = t*256 + w*64 + lane;
      int row = chunk >> 3, sp = chunk & 7;
      int sl = sp ^ (row & 7);
      gload_lds16(Bt + (size_t)(n0+row)*K + k0 + sl*8, &Bs[bsel][(t*256 + w*64)*8]);
    }
  };

  int nkt = K >> 6;
  stage(0, 0);
  __syncthreads();
  int cur = 0;
  for (int kt = 0; kt < nkt; ++kt) {
    if (kt + 1 < nkt) stage(kt + 1, cur ^ 1);
    #pragma unroll
    for (int s = 0; s < 2; ++s) {
      short8 af[2], bfr[4];
      #pragma unroll
      for (int mi = 0; mi < 2; ++mi) {
        int row = wr*32 + mi*16 + l15;
        int slot = (s*4 + l4) ^ (row & 7);
        af[mi] = *reinterpret_cast<const short8*>(&As[cur][row*64 + slot*8]);
      }
      #pragma unroll
      for (int ni = 0; ni < 4; ++ni) {
        int row = wc*64 + ni*16 + l15;
        int slot = (s*4 + l4) ^ (row & 7);
        bfr[ni] = *reinterpret_cast<const short8*>(&Bs[cur][row*64 + slot*8]);
      }
      #pragma unroll
      for (int mi = 0; mi < 2; ++mi)
        #pragma unroll
        for (int ni = 0; ni < 4; ++ni)
          acc[mi][ni] = __builtin_amdgcn_mfma_f32_16x16x32_bf16(af[mi], bfr[ni], acc[mi][ni], 0, 0, 0);
    }
    __syncthreads();
    cur ^= 1;
  }

  if (OUTMODE == 1) {
    #pragma unroll
    for (int mi = 0; mi < 2; ++mi)
      #pragma unroll
      for (int ni = 0; ni < 4; ++ni)
        #pragma unroll
        for (int r = 0; r < 4; ++r) {
          int row = m0 + wr*32 + mi*16 + l4*4 + r;
          int col = n0 + wc*64 + ni*16 + l15;
          ((float*)Cout)[(size_t)row*N + col] = acc[mi][ni][r];
        }
    return;
  }

  // OUTMODE 0: bias + RoPE + layout split. This wave owns cols [col0, col0+64) = one head.
  int col0 = n0 + wc*64;
  if (col0 < NQ + NKV) {
    #pragma unroll
    for (int mi = 0; mi < 2; ++mi) {
      #pragma unroll
      for (int r = 0; r < 4; ++r) {
        int row = m0 + wr*32 + mi*16 + l4*4 + r;   // token
        int b = row >> 11, s = row & 2047;
        #pragma unroll
        for (int ni = 0; ni < 2; ++ni) {
          int dp = ni*16 + l15;                    // 0..31
          float x1 = acc[mi][ni][r]   + bias[col0 + dp];
          float x2 = acc[mi][ni+2][r] + bias[col0 + dp + 32];
          float2 c2 = cs[s*32 + dp];
          if (col0 < NQ) {        // Q: rope + 0.125 scale
            int h = col0 >> 6;
            size_t base = ((size_t)(b*NH + h)*SEQ + s)*64;
            Qr[base + dp]      = f2bf((x1*c2.x - x2*c2.y) * 0.125f);
            Qr[base + dp + 32] = f2bf((x2*c2.x + x1*c2.y) * 0.125f);
          } else {                // K: rope
            int kvh = (col0 - NQ) >> 6;
            size_t base = ((size_t)(b*NKVH + kvh)*SEQ + s)*64;
            Kr[base + dp]      = f2bf(x1*c2.x - x2*c2.y);
            Kr[base + dp + 32] = f2bf(x2*c2.x + x1*c2.y);
          }
        }
      }
    }
  } else {
    // V: transpose 64dp x 32tok through wave-private padded LDS, then 16B stores.
    int kvh = (col0 - 1024) >> 6;
    unsigned short* scr = &Bs[0][0] + w * (64*40);   // 5KB per wave, 20KB total
    #pragma unroll
    for (int mi = 0; mi < 2; ++mi) {
      #pragma unroll
      for (int ni = 0; ni < 2; ++ni) {
        #pragma unroll
        for (int h2 = 0; h2 < 2; ++h2) {
          int dp = ni*16 + l15 + h2*32;
          float b0 = bias[col0 + dp];
          f32x4 a = acc[mi][ni + h2*2];
          uint2 pk;
          pk.x = cvt_pk_bf16(a[0] + b0, a[1] + b0);
          pk.y = cvt_pk_bf16(a[2] + b0, a[3] + b0);
          *reinterpret_cast<uint2*>(&scr[dp*40 + mi*16 + l4*4]) = pk;
        }
      }
    }
    __syncthreads();   // uniform within this block (all 4 waves are V-waves)
    int srow0 = m0 + wr*32;
    int b = srow0 >> 11, s0 = srow0 & 2047;
    size_t vbase = (size_t)(b*NKVH + kvh)*64;
    #pragma unroll
    for (int p2 = 0; p2 < 4; ++p2) {
      int dp = p2*16 + (lane >> 2);
      int tok0 = (lane & 3) * 8;
      short8 v = *reinterpret_cast<const short8*>(&scr[dp*40 + tok0]);
      *reinterpret_cast<short8*>(&Vt[(vbase + dp)*SEQ + s0 + tok0]) = v;
    }
  }
}

// ---------------- flash attention (causal, GQA) — intra-block split-K ----------------
// Block (i,h,b): 8 waves. Group 0 (waves 0-3): H-tile qtH=31-i, k-tiles 0..15 (16, no diag).
// Group 1 (waves 4-7): H-tile k-tiles 16..qtH (incl. diag), then L-tile qtL=i k 0..qtL.
// Exactly 17 serial tiles/group (was 32). Each group has its own double-buffered K/V
// stream. H output merged across groups via LDS (split-K rescale combine).
// Tile body/fragment maps/swizzles/defer-max identical to the R18-proven code.
__global__ __launch_bounds__(512, 2) void k_attn(
    const unsigned short* __restrict__ Q,   // [B][NH][S][64], pre-scaled by 0.125
    const unsigned short* __restrict__ Kr,  // [B][NKVH][S][64]
    const unsigned short* __restrict__ Vt,  // [B][NKVH][64][S]
    unsigned short* __restrict__ Aout) {    // [TOK][896]
  __shared__ __align__(16) unsigned short Kst[2][2][64*64];  // [grp][buf], 32 KB
  __shared__ __align__(16) unsigned short Vst[2][2][64*64];  // 32 KB
  __shared__ __align__(16) unsigned short P_lds[8][16*64];   // 16 KB, wave-private
  int lane = threadIdx.x & 63, w = threadIdx.x >> 6;   // w 0..7
  int grp = w >> 2, wsub = w & 3;
  int l15 = lane & 15, l4 = lane >> 4;
  int i = blockIdx.x, h = blockIdx.y, b = blockIdx.z;
  int qtH = 31 - i, qtL = i;
  int kvh = h / GQ;
  const unsigned short* Kb = Kr + ((size_t)(b*NKVH + kvh))*SEQ*64;
  const unsigned short* Vb = Vt + ((size_t)(b*NKVH + kvh))*64*SEQ;
  char* Pw = (char*)&P_lds[w][0];

  // stage one K-tile + V^T-tile into own group's buffer: 256 threads, 2 chunks each
  auto stage_g = [&](int ks, int bsel) {
    int t256 = threadIdx.x & 255;
    #pragma unroll
    for (int part = 0; part < 2; ++part) {
      int chunk = part*256 + t256;
      int row = chunk >> 3;
      int sl = (chunk & 7) ^ (row & 7);
      gload_lds16(Kb + (size_t)(ks*64 + row)*64 + sl*8, &Kst[grp][bsel][chunk*8]);
      gload_lds16(Vb + (size_t)row*SEQ + ks*64 + sl*8, &Vst[grp][bsel][chunk*8]);
    }
  };

  const unsigned short* QbH = Q + (((size_t)(b*NH + h))*SEQ + qtH*64 + wsub*16) * 64;
  const unsigned short* QbL = Q + (((size_t)(b*NH + h))*SEQ + qtL*64 + wsub*16) * 64;
  short8 qaH[2], qaL[2], qac[2];
  #pragma unroll
  for (int si = 0; si < 2; ++si) {
    qaH[si] = *reinterpret_cast<const short8*>(QbH + l15*64 + si*32 + l4*8);
    qaL[si] = *reinterpret_cast<const short8*>(QbL + l15*64 + si*32 + l4*8);
  }
  qac[0] = qaH[0]; qac[1] = qaH[1];

  f32x4 acc[4];
  #pragma unroll
  for (int n = 0; n < 4; ++n) acc[n] = fzero4();
  float m_run = -__builtin_inff(), l_run = 0.0f;   // lane-partial l
  // group1's saved H-partial state
  f32x4 aH0 = fzero4(), aH1 = fzero4(), aH2 = fzero4(), aH3 = fzero4();
  float mH_sv = -__builtin_inff(), lH_sv = 0.0f;

  int nH1 = qtH - 15;             // group1 H-phase tile count (1..16)
  stage_g(grp == 0 ? 0 : 16, 0);
  __syncthreads();
  int cur = 0;

  for (int it = 0; it < 17; ++it) {
    // prefetch own group's next tile
    if (grp == 0) {
      if (it + 1 < 16) stage_g(it + 1, cur ^ 1);
    } else {
      int nit = it + 1;
      if (nit < 17) stage_g(nit < nH1 ? 16 + nit : nit - nH1, cur ^ 1);
    }
    // group1 phase switch: save H-partial, reset state for L-tile
    if (grp == 1 && it == nH1) {
      mH_sv = m_run; lH_sv = l_run;
      aH0 = acc[0]; aH1 = acc[1]; aH2 = acc[2]; aH3 = acc[3];
      acc[0] = fzero4(); acc[1] = fzero4(); acc[2] = fzero4(); acc[3] = fzero4();
      m_run = -__builtin_inff(); l_run = 0.0f;
      qac[0] = qaL[0]; qac[1] = qaL[1];
    }
    bool active = (grp == 1) || (it < 16);
    if (active) {
      int ks, qtc;
      if (grp == 0)        { ks = it;           qtc = qtH; }
      else if (it < nH1)   { ks = 16 + it;      qtc = qtH; }
      else                 { ks = it - nH1;     qtc = qtL; }
      const unsigned short* Ks = &Kst[grp][cur][0];
      const unsigned short* Vs = &Vst[grp][cur][0];
      // ---- QK^T: S^T[k][q] (swapped operands), q = l15 ----
      f32x4 sa[4];
      #pragma unroll
      for (int n = 0; n < 4; ++n) sa[n] = fzero4();
      __builtin_amdgcn_s_setprio(1);
      #pragma unroll
      for (int si = 0; si < 2; ++si) {
        short8 kb[4];
        #pragma unroll
        for (int n = 0; n < 4; ++n) {
          int row = n*16 + l15;
          int slot = (si*4 + l4) ^ (row & 7);
          kb[n] = *reinterpret_cast<const short8*>(&Ks[row*64 + slot*8]);
        }
        #pragma unroll
        for (int n = 0; n < 4; ++n)
          sa[n] = __builtin_amdgcn_mfma_f32_16x16x32_bf16(kb[n], qac[si], sa[n], 0, 0, 0);
      }
      __builtin_amdgcn_s_setprio(0);
      if (ks == qtc) {   // diagonal tile: causal mask
        int q_glob = qtc*64 + wsub*16 + l15;
        #pragma unroll
        for (int n = 0; n < 4; ++n)
          #pragma unroll
          for (int r = 0; r < 4; ++r) {
            int kpos = ks*64 + n*16 + l4*4 + r;
            if (kpos > q_glob) sa[n][r] = -1e30f;
          }
      }
      // ---- online softmax with T13 defer-max ----
      float t0 = fmaxf(fmaxf(sa[0][0],sa[0][1]), fmaxf(sa[0][2],sa[0][3]));
      float t1 = fmaxf(fmaxf(sa[1][0],sa[1][1]), fmaxf(sa[1][2],sa[1][3]));
      float t2 = fmaxf(fmaxf(sa[2][0],sa[2][1]), fmaxf(sa[2][2],sa[2][3]));
      float t3 = fmaxf(fmaxf(sa[3][0],sa[3][1]), fmaxf(sa[3][2],sa[3][3]));
      float tmax = fmaxf(fmaxf(t0,t1), fmaxf(t2,t3));
      tmax = fmaxf(tmax, __shfl_xor(tmax, 16));
      tmax = fmaxf(tmax, __shfl_xor(tmax, 32));
      if (!__all(tmax <= m_run + 8.0f)) {
        float mn = fmaxf(m_run, tmax);
        float sc = __expf(m_run - mn);
        l_run *= sc;
        #pragma unroll
        for (int n = 0; n < 4; ++n) acc[n] *= sc;
        m_run = mn;
      }
      #pragma unroll
      for (int n = 0; n < 4; ++n)
        #pragma unroll
        for (int r = 0; r < 4; ++r) sa[n][r] = __expf(sa[n][r] - m_run);
      float s0 = (sa[0][0]+sa[0][1]) + (sa[0][2]+sa[0][3]);
      float s1 = (sa[1][0]+sa[1][1]) + (sa[1][2]+sa[1][3]);
      float s2 = (sa[2][0]+sa[2][1]) + (sa[2][2]+sa[2][3]);
      float s3 = (sa[3][0]+sa[3][1]) + (sa[3][2]+sa[3][3]);
      l_run += (s0+s1) + (s2+s3);
      // ---- pack P -> swizzled wave-private LDS ----
      #pragma unroll
      for (int n = 0; n < 4; ++n) {
        uint2 pk;
        pk.x = cvt_pk_bf16(sa[n][0], sa[n][1]);
        pk.y = cvt_pk_bf16(sa[n][2], sa[n][3]);
        int colbyte = n*32 + l4*8;
        int addr = l15*128 + ((((colbyte>>4) ^ (l15&7))) << 4) + (colbyte & 15);
        *reinterpret_cast<uint2*>(Pw + addr) = pk;
      }
      // ---- PV: O^T[d][q] ----
      __builtin_amdgcn_s_setprio(1);
      #pragma unroll
      for (int s2i = 0; s2i < 2; ++s2i) {
        int pslot = (s2i*4 + l4) ^ (l15 & 7);
        short8 pa = *reinterpret_cast<const short8*>(Pw + l15*128 + pslot*16);
        #pragma unroll
        for (int n = 0; n < 4; ++n) {
          int row = n*16 + l15;
          int vslot = (s2i*4 + l4) ^ (row & 7);
          short8 vb = *reinterpret_cast<const short8*>(&Vs[row*64 + vslot*8]);
          acc[n] = __builtin_amdgcn_mfma_f32_16x16x32_bf16(vb, pa, acc[n], 0, 0, 0);
        }
      }
      __builtin_amdgcn_s_setprio(0);
    }
    __syncthreads();
    cur ^= 1;
  }

  // ---- cross-group combine of H partials (group1 -> LDS -> group0) ----
  float* cb = (float*)&Kst[0][0][0];   // 21.5 KB scratch inside 32 KB Kst (dead now)
  int cidx = (wsub*64 + lane) * 21;    // stride 21 floats: conflict-free
  if (grp == 1) {
    cb[cidx+0] = mH_sv;
    cb[cidx+1] = lH_sv;
    #pragma unroll
    for (int r = 0; r < 4; ++r) {
      cb[cidx+2+r]  = aH0[r];
      cb[cidx+6+r]  = aH1[r];
      cb[cidx+10+r] = aH2[r];
      cb[cidx+14+r] = aH3[r];
    }
  }
  __syncthreads();
  int qt_out;
  if (grp == 0) {
    float m1 = cb[cidx+0], l1 = cb[cidx+1];
    float m = fmaxf(m_run, m1);
    float e0 = __expf(m_run - m), e1 = __expf(m1 - m);
    l_run = l_run*e0 + l1*e1;
    #pragma unroll
    for (int n = 0; n < 4; ++n)
      #pragma unroll
      for (int r = 0; r < 4; ++r)
        acc[n][r] = acc[n][r]*e0 + cb[cidx+2+n*4+r]*e1;
    qt_out = qtH;
  } else {
    qt_out = qtL;   // L state is complete (group1 covered all its k)
  }

  // epilogue: reduce lane-partial l across l4, normalize, transpose O^T -> O, write
  float lt = l_run;
  lt += __shfl_xor(lt, 16);
  lt += __shfl_xor(lt, 32);
  float inv = 1.0f / lt;
  #pragma unroll
  for (int n = 0; n < 4; ++n) {
    uint2 pk;
    pk.x = cvt_pk_bf16(acc[n][0]*inv, acc[n][1]*inv);
    pk.y = cvt_pk_bf16(acc[n][2]*inv, acc[n][3]*inv);
    int colbyte = n*32 + l4*8;
    int addr = l15*128 + ((((colbyte>>4) ^ (l15&7))) << 4) + (colbyte & 15);
    *reinterpret_cast<uint2*>(Pw + addr) = pk;
  }
  int row = lane >> 2;
  int cb0 = (lane & 3) * 32;
  #pragma unroll
  for (int it = 0; it < 2; ++it) {
    int cbyte = cb0 + it*16;
    int slot = (cbyte >> 4) ^ (row & 7);
    short8 v = *reinterpret_cast<const short8*>(Pw + row*128 + slot*16);
    size_t tok = (size_t)b*SEQ + qt_out*64 + wsub*16 + row;
    *reinterpret_cast<short8*>(&Aout[tok*NQ + h*64 + (cbyte>>1)]) = v;
  }
}

// ---------------- launcher ----------------
extern "C" void kernel_launch(void* const* d_in, const int* in_sizes, int n_in,
                              void* d_out, int out_size, void* d_ws, size_t ws_size,
                              hipStream_t stream) {
  const float* hs = (const float*)d_in[0];
  const float* wq = (const float*)d_in[1];
  const float* bq = (const float*)d_in[2];
  const float* wk = (const float*)d_in[3];
  const float* bk = (const float*)d_in[4];
  const float* wv = (const float*)d_in[5];
  const float* bv = (const float*)d_in[6];
  const float* wo = (const float*)d_in[7];
  float* out = (float*)d_out;

  char* p = (char*)d_ws;
  auto alloc = [&](size_t bytes) { char* r = p; p += (bytes + 255) & ~(size_t)255; return r; };
  unsigned short* hb    = (unsigned short*)alloc((size_t)TOK*HID*2);
  unsigned short* wqkvt = (unsigned short*)alloc((size_t)NQKV*HID*2);
  unsigned short* wot   = (unsigned short*)alloc((size_t)HID*NQ*2);
  float*          bqkv  = (float*)alloc(NQKV*4);
  float2*         cs    = (float2*)alloc((size_t)SEQ*32*8);
  unsigned short* q_r   = (unsigned short*)alloc((size_t)BATCH*NH*SEQ*DH*2);
  unsigned short* k_r   = (unsigned short*)alloc((size_t)BATCH*NKVH*SEQ*DH*2);
  unsigned short* v_t   = (unsigned short*)alloc((size_t)BATCH*NKVH*DH*SEQ*2);
  unsigned short* attn  = (unsigned short*)alloc((size_t)TOK*NQ*2);

  k_prep<<<PREP_BLKS, 256, 0, stream>>>(hs, wq, bq, wk, bk, wv, bv, wo,
                                        hb, wqkvt, wot, bqkv, cs);
  // GEMM1 with fused bias+RoPE+layout epilogue -> q_r/k_r/v_t
  k_gemm_bt<0><<<dim3(NQKV/128, TOK/64), 256, 0, stream>>>(
      hb, wqkvt, bqkv, cs, nullptr, q_r, k_r, v_t, TOK, NQKV, HID);
  k_attn<<<dim3(16, NH, BATCH), 512, 0, stream>>>(q_r, k_r, v_t, attn);
  k_gemm_bt<1><<<dim3(NQ/128, TOK/64), 256, 0, stream>>>(
      attn, wot, nullptr, nullptr, out, nullptr, nullptr, nullptr, TOK, NQ, HID);
}

// Round 20
// 86.660 us; speedup vs baseline: 1.1534x; 1.1534x over previous
//
#include <hip/hip_runtime.h>

#define HID 896
#define NQ 896
#define NKV 128
#define NQKV 1152
#define NH 14
#define NKVH 2
#define GQ 7
#define DH 64
#define SEQ 2048
#define BATCH 2
#define TOK (BATCH*SEQ)

typedef __attribute__((ext_vector_type(8))) short short8;    // 8 bf16 (4 VGPRs)
typedef __attribute__((ext_vector_type(4))) float f32x4;
typedef __attribute__((ext_vector_type(4))) unsigned short us4;

__device__ __forceinline__ unsigned short f2bf(float x) {
  unsigned int u = __builtin_bit_cast(unsigned int, x);
  u = (u + 0x7fffu + ((u >> 16) & 1u)) >> 16;
  return (unsigned short)u;
}
__device__ __forceinline__ float bf2f(unsigned short b) {
  return __builtin_bit_cast(float, (unsigned int)b << 16);
}
__device__ __forceinline__ f32x4 fzero4() {
  f32x4 z; z[0]=0.f; z[1]=0.f; z[2]=0.f; z[3]=0.f; return z;
}
__device__ __forceinline__ unsigned int cvt_pk_bf16(float lo, float hi) {
  unsigned int r;
  asm("v_cvt_pk_bf16_f32 %0, %1, %2" : "=v"(r) : "v"(lo), "v"(hi));
  return r;
}
__device__ __forceinline__ void gload_lds16(const unsigned short* g, unsigned short* l) {
  __builtin_amdgcn_global_load_lds(
      (const __attribute__((address_space(1))) void*)(const void*)g,
      (__attribute__((address_space(3))) void*)(void*)l, 16, 0, 0);
}

// ---------------- fused prep: cvt + 4 weight transposes + bias + rope tables ----------------
#define CVT_BLKS 3584   // TOK*HID/4/256
#define TRN_BLKS 448    // 196 (wq) + 28 (wk) + 28 (wv) + 196 (wo)
#define BIAS_BLKS 5
#define TAB_BLKS 256    // SEQ*32/256
#define PREP_BLKS (CVT_BLKS + TRN_BLKS + BIAS_BLKS + TAB_BLKS)

__global__ void k_prep(const float* __restrict__ hs,
                       const float* __restrict__ wq, const float* __restrict__ bq,
                       const float* __restrict__ wk, const float* __restrict__ bk,
                       const float* __restrict__ wv, const float* __restrict__ bv,
                       const float* __restrict__ wo,
                       unsigned short* __restrict__ hb,
                       unsigned short* __restrict__ wqkvt,
                       unsigned short* __restrict__ wot,
                       float* __restrict__ bqkv,
                       float2* __restrict__ cs) {
  __shared__ unsigned short Ls[64*65];
  int blk = blockIdx.x, tid = threadIdx.x;
  if (blk < CVT_BLKS) {  // hidden fp32 -> bf16
    int i = blk*256 + tid;
    float4 v = ((const float4*)hs)[i];
    us4 o; o[0]=f2bf(v.x); o[1]=f2bf(v.y); o[2]=f2bf(v.z); o[3]=f2bf(v.w);
    ((us4*)hb)[i] = o;
    return;
  }
  blk -= CVT_BLKS;
  if (blk < TRN_BLKS) {  // W [K][N] fp32 -> out [N][K] bf16, 64x64 tile
    const float* W; unsigned short* out; int K, N, n0, k0;
    if (blk < 196)      { W=wq; out=wqkvt;                        K=HID; N=NQ;  int t=blk;     n0=(t%14)*64; k0=(t/14)*64; }
    else if (blk < 224) { W=wk; out=wqkvt + (size_t)NQ*HID;       K=HID; N=NKV; int t=blk-196; n0=(t%2)*64;  k0=(t/2)*64; }
    else if (blk < 252) { W=wv; out=wqkvt + (size_t)(NQ+NKV)*HID; K=HID; N=NKV; int t=blk-224; n0=(t%2)*64;  k0=(t/2)*64; }
    else                { W=wo; out=wot;                          K=NQ;  N=HID; int t=blk-252; n0=(t%14)*64; k0=(t/14)*64; }
    #pragma unroll
    for (int i = 0; i < 16; ++i) {
      int idx = i*256 + tid;
      int r = idx >> 6, c = idx & 63;
      Ls[c*65 + r] = f2bf(W[(size_t)(k0 + r)*N + n0 + c]);
    }
    __syncthreads();
    #pragma unroll
    for (int i = 0; i < 16; ++i) {
      int idx = i*256 + tid;
      int r2 = idx >> 6, c2 = idx & 63;
      out[(size_t)(n0 + r2)*K + k0 + c2] = Ls[r2*65 + c2];
    }
    return;
  }
  blk -= TRN_BLKS;
  if (blk < BIAS_BLKS) {
    int i = blk*256 + tid;
    if (i < NQKV) {
      if (i < NQ) bqkv[i] = bq[i];
      else if (i < NQ + NKV) bqkv[i] = bk[i - NQ];
      else bqkv[i] = bv[i - NQ - NKV];
    }
    return;
  }
  blk -= BIAS_BLKS;
  {  // rope tables (paired cos/sin), SEQ*32 entries
    int i = blk*256 + tid;
    int s = i >> 5, dp = i & 31;
    float inv = __expf(-(float)(2*dp) * (13.815510557964274f / 64.0f));
    float f = (float)s * inv;
    cs[i] = make_float2(cosf(f), sinf(f));
  }
}

// ---------------- GEMM: C[M][N] = A[M][K] @ Bt[N][K]^T, BM=64 BN=128 BK=64 ----------------
// 2-phase prefetch double-buffer: stage(next) || compute(cur), ONE barrier per K-step.
// OUTMODE 0: fused bias + RoPE + layout-split epilogue -> Qr/Kr/Vt (bf16).
// OUTMODE 1: plain fp32 C
template<int OUTMODE>
__global__ __launch_bounds__(256, 3) void k_gemm_bt(
    const unsigned short* __restrict__ A,
    const unsigned short* __restrict__ Bt,
    const float* __restrict__ bias,
    const float2* __restrict__ cs,
    void* __restrict__ Cout,
    unsigned short* __restrict__ Qr,
    unsigned short* __restrict__ Kr,
    unsigned short* __restrict__ Vt,
    int M, int N, int K) {
  __shared__ unsigned short As[2][64*64];    // 16 KB
  __shared__ unsigned short Bs[2][128*64];   // 32 KB
  int tid = threadIdx.x;
  int lane = tid & 63, w = tid >> 6;
  int wr = w >> 1, wc = w & 1;
  int l15 = lane & 15, l4 = lane >> 4;
  int m0 = blockIdx.y * 64, n0 = blockIdx.x * 128;

  f32x4 acc[2][4];
  #pragma unroll
  for (int i = 0; i < 2; ++i)
    #pragma unroll
    for (int j = 0; j < 4; ++j) acc[i][j] = fzero4();

  auto stage = [&](int kt, int bsel) {
    int k0 = kt << 6;
    #pragma unroll
    for (int t = 0; t < 2; ++t) {
      int chunk = t*256 + w*64 + lane;
      int row = chunk >> 3, sp = chunk & 7;
      int sl = sp ^ (row & 7);
      gload_lds16(A + (size_t)(m0+row)*K + k0 + sl*8, &As[bsel][(t*256 + w*64)*8]);
    }
    #pragma unroll
    for (int t = 0; t < 4; ++t) {
      int chunk = t*256 + w*64 + lane;
      int row = chunk >> 3, sp = chunk & 7;
      int sl = sp ^ (row & 7);
      gload_lds16(Bt + (size_t)(n0+row)*K + k0 + sl*8, &Bs[bsel][(t*256 + w*64)*8]);
    }
  };

  int nkt = K >> 6;
  stage(0, 0);
  __syncthreads();
  int cur = 0;
  for (int kt = 0; kt < nkt; ++kt) {
    if (kt + 1 < nkt) stage(kt + 1, cur ^ 1);
    #pragma unroll
    for (int s = 0; s < 2; ++s) {
      short8 af[2], bfr[4];
      #pragma unroll
      for (int mi = 0; mi < 2; ++mi) {
        int row = wr*32 + mi*16 + l15;
        int slot = (s*4 + l4) ^ (row & 7);
        af[mi] = *reinterpret_cast<const short8*>(&As[cur][row*64 + slot*8]);
      }
      #pragma unroll
      for (int ni = 0; ni < 4; ++ni) {
        int row = wc*64 + ni*16 + l15;
        int slot = (s*4 + l4) ^ (row & 7);
        bfr[ni] = *reinterpret_cast<const short8*>(&Bs[cur][row*64 + slot*8]);
      }
      #pragma unroll
      for (int mi = 0; mi < 2; ++mi)
        #pragma unroll
        for (int ni = 0; ni < 4; ++ni)
          acc[mi][ni] = __builtin_amdgcn_mfma_f32_16x16x32_bf16(af[mi], bfr[ni], acc[mi][ni], 0, 0, 0);
    }
    __syncthreads();
    cur ^= 1;
  }

  if (OUTMODE == 1) {
    #pragma unroll
    for (int mi = 0; mi < 2; ++mi)
      #pragma unroll
      for (int ni = 0; ni < 4; ++ni)
        #pragma unroll
        for (int r = 0; r < 4; ++r) {
          int row = m0 + wr*32 + mi*16 + l4*4 + r;
          int col = n0 + wc*64 + ni*16 + l15;
          ((float*)Cout)[(size_t)row*N + col] = acc[mi][ni][r];
        }
    return;
  }

  // OUTMODE 0: bias + RoPE + layout split. This wave owns cols [col0, col0+64) = one head.
  int col0 = n0 + wc*64;
  if (col0 < NQ + NKV) {
    #pragma unroll
    for (int mi = 0; mi < 2; ++mi) {
      #pragma unroll
      for (int r = 0; r < 4; ++r) {
        int row = m0 + wr*32 + mi*16 + l4*4 + r;   // token
        int b = row >> 11, s = row & 2047;
        #pragma unroll
        for (int ni = 0; ni < 2; ++ni) {
          int dp = ni*16 + l15;                    // 0..31
          float x1 = acc[mi][ni][r]   + bias[col0 + dp];
          float x2 = acc[mi][ni+2][r] + bias[col0 + dp + 32];
          float2 c2 = cs[s*32 + dp];
          if (col0 < NQ) {        // Q: rope + 0.125 scale
            int h = col0 >> 6;
            size_t base = ((size_t)(b*NH + h)*SEQ + s)*64;
            Qr[base + dp]      = f2bf((x1*c2.x - x2*c2.y) * 0.125f);
            Qr[base + dp + 32] = f2bf((x2*c2.x + x1*c2.y) * 0.125f);
          } else {                // K: rope
            int kvh = (col0 - NQ) >> 6;
            size_t base = ((size_t)(b*NKVH + kvh)*SEQ + s)*64;
            Kr[base + dp]      = f2bf(x1*c2.x - x2*c2.y);
            Kr[base + dp + 32] = f2bf(x2*c2.x + x1*c2.y);
          }
        }
      }
    }
  } else {
    // V: transpose 64dp x 32tok through wave-private padded LDS, then 16B stores.
    int kvh = (col0 - 1024) >> 6;
    unsigned short* scr = &Bs[0][0] + w * (64*40);   // 5KB per wave, 20KB total
    #pragma unroll
    for (int mi = 0; mi < 2; ++mi) {
      #pragma unroll
      for (int ni = 0; ni < 2; ++ni) {
        #pragma unroll
        for (int h2 = 0; h2 < 2; ++h2) {
          int dp = ni*16 + l15 + h2*32;
          float b0 = bias[col0 + dp];
          f32x4 a = acc[mi][ni + h2*2];
          uint2 pk;
          pk.x = cvt_pk_bf16(a[0] + b0, a[1] + b0);
          pk.y = cvt_pk_bf16(a[2] + b0, a[3] + b0);
          *reinterpret_cast<uint2*>(&scr[dp*40 + mi*16 + l4*4]) = pk;
        }
      }
    }
    __syncthreads();   // uniform within this block (all 4 waves are V-waves)
    int srow0 = m0 + wr*32;
    int b = srow0 >> 11, s0 = srow0 & 2047;
    size_t vbase = (size_t)(b*NKVH + kvh)*64;
    #pragma unroll
    for (int p2 = 0; p2 < 4; ++p2) {
      int dp = p2*16 + (lane >> 2);
      int tok0 = (lane & 3) * 8;
      short8 v = *reinterpret_cast<const short8*>(&scr[dp*40 + tok0]);
      *reinterpret_cast<short8*>(&Vt[(vbase + dp)*SEQ + s0 + tok0]) = v;
    }
  }
}

// ---------------- flash attention (causal, GQA) ----------------
// R13/R16 green structure: paired q-tiles (heavy 31-i / light i) computed by PARALLEL
// wave groups (8 waves), 2-tile slabs double-buffered, lane-partial l_run,
// slab-combined softmax + T13 defer-max (R18 best build).
__global__ __launch_bounds__(512, 2) void k_attn(
    const unsigned short* __restrict__ Q,   // [B][NH][S][64], pre-scaled by 0.125
    const unsigned short* __restrict__ Kr,  // [B][NKVH][S][64]
    const unsigned short* __restrict__ Vt,  // [B][NKVH][64][S]
    unsigned short* __restrict__ Aout) {    // [TOK][896]
  __shared__ __align__(16) unsigned short Kst[2][2][64*64];  // 32 KB [buf][tile]
  __shared__ __align__(16) unsigned short Vst[2][2][64*64];  // 32 KB
  __shared__ __align__(16) unsigned short P_lds[8][16*64];   // 16 KB, wave-private
  int lane = threadIdx.x & 63, w = threadIdx.x >> 6;   // w 0..7
  int grp = w >> 2, wsub = w & 3;
  int l15 = lane & 15, l4 = lane >> 4;
  int i = blockIdx.x, h = blockIdx.y, b = blockIdx.z;
  int qtH = 31 - i, qtL = i;
  int qt = grp ? qtL : qtH;          // this wave's q-tile
  int kvh = h / GQ;
  const unsigned short* Kb = Kr + ((size_t)(b*NKVH + kvh))*SEQ*64;
  const unsigned short* Vb = Vt + ((size_t)(b*NKVH + kvh))*64*SEQ;
  char* Pw = (char*)&P_lds[w][0];

  // stage 2-tile slab into buffer bsel; 512 threads: 1 chunk per tile per array
  auto stage = [&](int slab, int bsel) {
    #pragma unroll
    for (int t = 0; t < 2; ++t) {
      int ks = slab*2 + t; if (ks > 31) ks = 31;   // clamp: in-bounds, unused
      int chunk = w*64 + lane;          // 0..511
      int row = chunk >> 3;
      int sl = (chunk & 7) ^ (row & 7);
      gload_lds16(Kb + (size_t)(ks*64 + row)*64 + sl*8, &Kst[bsel][t][chunk*8]);
      gload_lds16(Vb + (size_t)row*SEQ + ks*64 + sl*8, &Vst[bsel][t][chunk*8]);
    }
  };

  const unsigned short* Qb = Q + (((size_t)(b*NH + h))*SEQ + qt*64 + wsub*16) * 64;
  short8 qa[2];
  #pragma unroll
  for (int s = 0; s < 2; ++s)
    qa[s] = *reinterpret_cast<const short8*>(Qb + l15*64 + s*32 + l4*8);

  f32x4 acc[4];
  #pragma unroll
  for (int n = 0; n < 4; ++n) acc[n] = fzero4();
  float m_run = -__builtin_inff(), l_run = 0.0f;   // l_run lane-PARTIAL (own 16 k's)

  stage(0, 0);
  __syncthreads();
  int cur = 0;
  int nkt = qtH + 1;
  int nslab = (nkt + 1) >> 1;

  for (int s = 0; s < nslab; ++s) {
    if (s + 1 < nslab) stage(s + 1, cur ^ 1);
    int ks0 = s*2;
    if (ks0 <= qt) {   // wave-uniform: at least tile 0 is valid for this wave
      // ---- phase 1: QK^T for both tiles (16 independent MFMAs) ----
      f32x4 sa[2][4];
      #pragma unroll
      for (int t = 0; t < 2; ++t) {
        int ks = ks0 + t;
        if (ks <= qt) {
          const unsigned short* Ks = &Kst[cur][t][0];
          #pragma unroll
          for (int n = 0; n < 4; ++n) sa[t][n] = fzero4();
          __builtin_amdgcn_s_setprio(1);
          #pragma unroll
          for (int si = 0; si < 2; ++si) {
            short8 kb[4];
            #pragma unroll
            for (int n = 0; n < 4; ++n) {
              int row = n*16 + l15;
              int slot = (si*4 + l4) ^ (row & 7);
              kb[n] = *reinterpret_cast<const short8*>(&Ks[row*64 + slot*8]);
            }
            #pragma unroll
            for (int n = 0; n < 4; ++n)   // swapped: A=K-frag, B=Q-frag -> S^T[k][q]
              sa[t][n] = __builtin_amdgcn_mfma_f32_16x16x32_bf16(kb[n], qa[si], sa[t][n], 0, 0, 0);
          }
          __builtin_amdgcn_s_setprio(0);
          if (ks == qt) {  // diagonal tile: causal mask
            int q_glob = qt*64 + wsub*16 + l15;
            #pragma unroll
            for (int n = 0; n < 4; ++n)
              #pragma unroll
              for (int r = 0; r < 4; ++r) {
                int kpos = ks*64 + n*16 + l4*4 + r;
                if (kpos > q_glob) sa[t][n][r] = -1e30f;
              }
          }
        } else {
          #pragma unroll
          for (int n = 0; n < 4; ++n)
            #pragma unroll
            for (int r = 0; r < 4; ++r) sa[t][n][r] = -1e30f;   // exp -> 0
        }
      }
      // ---- phase 2: combined online-softmax over 128 k-values, with T13 defer-max ----
      float tm[2];
      #pragma unroll
      for (int t = 0; t < 2; ++t) {
        float t0 = fmaxf(fmaxf(sa[t][0][0],sa[t][0][1]), fmaxf(sa[t][0][2],sa[t][0][3]));
        float t1 = fmaxf(fmaxf(sa[t][1][0],sa[t][1][1]), fmaxf(sa[t][1][2],sa[t][1][3]));
        float t2 = fmaxf(fmaxf(sa[t][2][0],sa[t][2][1]), fmaxf(sa[t][2][2],sa[t][2][3]));
        float t3 = fmaxf(fmaxf(sa[t][3][0],sa[t][3][1]), fmaxf(sa[t][3][2],sa[t][3][3]));
        tm[t] = fmaxf(fmaxf(t0,t1), fmaxf(t2,t3));
      }
      float tmax = fmaxf(tm[0], tm[1]);
      tmax = fmaxf(tmax, __shfl_xor(tmax, 16));
      tmax = fmaxf(tmax, __shfl_xor(tmax, 32));
      // T13: skip the rescale when max grew by < 8 (P bounded by e^8, bf16-safe)
      if (!__all(tmax <= m_run + 8.0f)) {
        float mn = fmaxf(m_run, tmax);
        float sc = __expf(m_run - mn);
        l_run *= sc;
        #pragma unroll
        for (int n = 0; n < 4; ++n) acc[n] *= sc;
        m_run = mn;
      }
      float sum = 0.0f;
      #pragma unroll
      for (int t = 0; t < 2; ++t) {
        #pragma unroll
        for (int n = 0; n < 4; ++n)
          #pragma unroll
          for (int r = 0; r < 4; ++r) sa[t][n][r] = __expf(sa[t][n][r] - m_run);
        float s0 = (sa[t][0][0]+sa[t][0][1]) + (sa[t][0][2]+sa[t][0][3]);
        float s1 = (sa[t][1][0]+sa[t][1][1]) + (sa[t][1][2]+sa[t][1][3]);
        float s2 = (sa[t][2][0]+sa[t][2][1]) + (sa[t][2][2]+sa[t][2][3]);
        float s3 = (sa[t][3][0]+sa[t][3][1]) + (sa[t][3][2]+sa[t][3][3]);
        sum += (s0+s1) + (s2+s3);
      }
      l_run += sum;        // lane-partial; reduced once in epilogue
      // ---- phase 3: pack + PV per valid tile ----
      #pragma unroll
      for (int t = 0; t < 2; ++t) {
        if (ks0 + t <= qt) {
          #pragma unroll
          for (int n = 0; n < 4; ++n) {
            uint2 pk;
            pk.x = cvt_pk_bf16(sa[t][n][0], sa[t][n][1]);
            pk.y = cvt_pk_bf16(sa[t][n][2], sa[t][n][3]);
            int colbyte = n*32 + l4*8;
            int addr = l15*128 + ((((colbyte>>4) ^ (l15&7))) << 4) + (colbyte & 15);
            *reinterpret_cast<uint2*>(Pw + addr) = pk;
          }
          const unsigned short* Vs = &Vst[cur][t][0];
          __builtin_amdgcn_s_setprio(1);
          #pragma unroll
          for (int s2i = 0; s2i < 2; ++s2i) {
            int pslot = (s2i*4 + l4) ^ (l15 & 7);
            short8 pa = *reinterpret_cast<const short8*>(Pw + l15*128 + pslot*16);
            #pragma unroll
            for (int n = 0; n < 4; ++n) {
              int row = n*16 + l15;
              int vslot = (s2i*4 + l4) ^ (row & 7);
              short8 vb = *reinterpret_cast<const short8*>(&Vs[row*64 + vslot*8]);
              acc[n] = __builtin_amdgcn_mfma_f32_16x16x32_bf16(vb, pa, acc[n], 0, 0, 0);
            }
          }
          __builtin_amdgcn_s_setprio(0);
        }
      }
    }
    __syncthreads();
    cur ^= 1;
  }

  // epilogue: reduce lane-partial l across l4, normalize, transpose O^T -> O, write
  float lt = l_run;
  lt += __shfl_xor(lt, 16);
  lt += __shfl_xor(lt, 32);
  float inv = 1.0f / lt;
  #pragma unroll
  for (int n = 0; n < 4; ++n) {
    uint2 pk;
    pk.x = cvt_pk_bf16(acc[n][0]*inv, acc[n][1]*inv);
    pk.y = cvt_pk_bf16(acc[n][2]*inv, acc[n][3]*inv);
    int colbyte = n*32 + l4*8;
    int addr = l15*128 + ((((colbyte>>4) ^ (l15&7))) << 4) + (colbyte & 15);
    *reinterpret_cast<uint2*>(Pw + addr) = pk;
  }
  int row = lane >> 2;
  int cb0 = (lane & 3) * 32;
  #pragma unroll
  for (int it = 0; it < 2; ++it) {
    int cb = cb0 + it*16;
    int slot = (cb >> 4) ^ (row & 7);
    short8 v = *reinterpret_cast<const short8*>(Pw + row*128 + slot*16);
    size_t tok = (size_t)b*SEQ + qt*64 + wsub*16 + row;
    *reinterpret_cast<short8*>(&Aout[tok*NQ + h*64 + (cb>>1)]) = v;
  }
}

// ---------------- launcher ----------------
extern "C" void kernel_launch(void* const* d_in, const int* in_sizes, int n_in,
                              void* d_out, int out_size, void* d_ws, size_t ws_size,
                              hipStream_t stream) {
  const float* hs = (const float*)d_in[0];
  const float* wq = (const float*)d_in[1];
  const float* bq = (const float*)d_in[2];
  const float* wk = (const float*)d_in[3];
  const float* bk = (const float*)d_in[4];
  const float* wv = (const float*)d_in[5];
  const float* bv = (const float*)d_in[6];
  const float* wo = (const float*)d_in[7];
  float* out = (float*)d_out;

  char* p = (char*)d_ws;
  auto alloc = [&](size_t bytes) { char* r = p; p += (bytes + 255) & ~(size_t)255; return r; };
  unsigned short* hb    = (unsigned short*)alloc((size_t)TOK*HID*2);
  unsigned short* wqkvt = (unsigned short*)alloc((size_t)NQKV*HID*2);
  unsigned short* wot   = (unsigned short*)alloc((size_t)HID*NQ*2);
  float*          bqkv  = (float*)alloc(NQKV*4);
  float2*         cs    = (float2*)alloc((size_t)SEQ*32*8);
  unsigned short* q_r   = (unsigned short*)alloc((size_t)BATCH*NH*SEQ*DH*2);
  unsigned short* k_r   = (unsigned short*)alloc((size_t)BATCH*NKVH*SEQ*DH*2);
  unsigned short* v_t   = (unsigned short*)alloc((size_t)BATCH*NKVH*DH*SEQ*2);
  unsigned short* attn  = (unsigned short*)alloc((size_t)TOK*NQ*2);

  k_prep<<<PREP_BLKS, 256, 0, stream>>>(hs, wq, bq, wk, bk, wv, bv, wo,
                                        hb, wqkvt, wot, bqkv, cs);
  // GEMM1 with fused bias+RoPE+layout epilogue -> q_r/k_r/v_t
  k_gemm_bt<0><<<dim3(NQKV/128, TOK/64), 256, 0, stream>>>(
      hb, wqkvt, bqkv, cs, nullptr, q_r, k_r, v_t, TOK, NQKV, HID);
  k_attn<<<dim3(16, NH, BATCH), 512, 0, stream>>>(q_r, k_r, v_t, attn);
  k_gemm_bt<1><<<dim3(NQ/128, TOK/64), 256, 0, stream>>>(
      attn, wot, nullptr, nullptr, out, nullptr, nullptr, nullptr, TOK, NQ, HID);
}